// Round 11
// baseline (159.982 us; speedup 1.0000x reference)
//
#include <hip/hip_runtime.h>

typedef __attribute__((ext_vector_type(4))) float f32x4;
typedef __attribute__((ext_vector_type(8))) short bf16x8;
typedef __attribute__((ext_vector_type(4))) short bf16x4;

#define MEMBAR() asm volatile("" ::: "memory")

__device__ __forceinline__ unsigned short f2bf(float f) {
  unsigned int u = __builtin_bit_cast(unsigned int, f);
  u += 0x7FFFu + ((u >> 16) & 1u);   // RTNE
  return (unsigned short)(u >> 16);
}

// ---- K0a: P[b][h] = b_attn[h] + dot(W_attn[h, 0:512], hidden[b, :])
__global__ __launch_bounds__(256) void k_prep_p(
    const float* __restrict__ hidden, const float* __restrict__ W,
    const float* __restrict__ bias, float* __restrict__ P) {
  __shared__ float hsh[512];
  const int b = blockIdx.x;
  for (int i = threadIdx.x; i < 512; i += 256) hsh[i] = hidden[b * 512 + i];
  __syncthreads();
  for (int h = threadIdx.x; h < 512; h += 256) {
    const float* wr = W + (long)h * 1536;
    float s = 0.f;
#pragma unroll 4
    for (int f = 0; f < 512; f += 4) {
      float4 wv = *reinterpret_cast<const float4*>(wr + f);
      s += wv.x * hsh[f] + wv.y * hsh[f + 1] + wv.z * hsh[f + 2] + wv.w * hsh[f + 3];
    }
    P[b * 512 + h] = bias[h] + s;
  }
}

// ---- K0b: W2t[kb][h][kk] = bf16(W_attn[h][512 + kb*32 + kk]),  kb<32, h<512, kk<32
__global__ __launch_bounds__(256) void k_prep_w(
    const float* __restrict__ W, unsigned short* __restrict__ W2t) {
  const int id = blockIdx.x * 256 + threadIdx.x;  // 65536 threads, 8 elems each
  const int kk8 = (id & 3) * 8;
  const int h = (id >> 2) & 511;
  const int kb = id >> 11;
  const float* src = W + (long)h * 1536 + 512 + kb * 32 + kk8;
  float4 a = *reinterpret_cast<const float4*>(src);
  float4 c = *reinterpret_cast<const float4*>(src + 4);
  union { unsigned short u[8]; bf16x8 v; } o;
  o.u[0] = f2bf(a.x); o.u[1] = f2bf(a.y); o.u[2] = f2bf(a.z); o.u[3] = f2bf(a.w);
  o.u[4] = f2bf(c.x); o.u[5] = f2bf(c.y); o.u[6] = f2bf(c.z); o.u[7] = f2bf(c.w);
  *reinterpret_cast<bf16x8*>(W2t + (long)kb * 16384 + h * 32 + kk8) = o.v;
}

// ---- K1: fused GEMM + tanh + v-reduce -> logits (complete per block)
// 1024 blocks x 512 thr = 8 waves; wave w: 64 rows x cols [w*64, w*64+64).
// Round-9 champion structure (reg-staged bf16 LDS, XOR swizzle, raw s_barrier,
// no vmcnt drains) with BK=64 per barrier: 16 barrier-iters, each processing
// two 32-k sub-tiles (32 MFMAs/barrier). Stage footprint kept at the scale the
// compiler provably honors (2 f32x4 raws + 2 B-sets of 4 bf16x8).
__global__ __launch_bounds__(512, 2) void k_main(
    const float* __restrict__ enc, const short* __restrict__ W2t,
    const float* __restrict__ P, const float* __restrict__ v,
    float* __restrict__ logits) {
  __shared__ short As[4][2048];        // 4 sub-bufs x [64 rows][32 k] bf16 = 16 KB
  __shared__ float attred[64][8];

  const int tid = threadIdx.x;
  const int lane = tid & 63;
  const int w = tid >> 6;               // 0..7: col panel
  const int hl = lane & 15, kg = lane >> 4;
  const long rowbase = (long)blockIdx.x * 64;
  const int b = (int)(rowbase >> 12);   // 64 | 4096

  // staging: thread -> row r = tid>>3, chunk c = tid&7 (4 floats at k=c*4)
  const int r = tid >> 3, c = tid & 7;
  const f32x4* gp = reinterpret_cast<const f32x4*>(enc + (rowbase + r) * 1024);
  // swizzled write offset (shorts) within a sub-buffer (identical to round 9)
  const int wr_off = r * 32 + ((((c >> 1) ^ ((r >> 1) & 3)) << 3)) + ((c & 1) << 2);
  // frag read offset (shorts): row = mi*16+hl, slot = kg ^ ((hl>>1)&3)
  const int base_f = hl * 32 + ((kg ^ ((hl >> 1) & 3)) << 3);
  // B: h = w*64 + ni*16 + hl; elem = kb*16384 + h*32 + kg*8
  const short* bp = W2t + (w * 64 + hl) * 32 + kg * 8;

  f32x4 acc[4][4];
#pragma unroll
  for (int mi = 0; mi < 4; ++mi)
#pragma unroll
    for (int ni = 0; ni < 4; ++ni) acc[mi][ni] = (f32x4){0.f, 0.f, 0.f, 0.f};

  bf16x8 Se[4], So[4];       // B sets for even / odd 32-k slabs
  f32x4 rawA, rawB;          // next iter's two sub-tile chunks (this thread)

#define CVT4W(BUF, RAW) {                                             \
    union { __bf16 h[4]; bf16x4 s; } _u;                              \
    _u.h[0] = (__bf16)(RAW)[0]; _u.h[1] = (__bf16)(RAW)[1];           \
    _u.h[2] = (__bf16)(RAW)[2]; _u.h[3] = (__bf16)(RAW)[3];           \
    *reinterpret_cast<bf16x4*>(&As[(BUF)][wr_off]) = _u.s;            \
  }
#define LOADB(DST, KB) {                                              \
    const short* _k = bp + (KB) * 16384;                              \
    DST[0] = *reinterpret_cast<const bf16x8*>(_k);                    \
    DST[1] = *reinterpret_cast<const bf16x8*>(_k + 512);              \
    DST[2] = *reinterpret_cast<const bf16x8*>(_k + 1024);             \
    DST[3] = *reinterpret_cast<const bf16x8*>(_k + 1536);             \
  }
#define MFMA16(AB, BS) {                                              \
    bf16x8 _f0 = *reinterpret_cast<const bf16x8*>((AB) + base_f);     \
    bf16x8 _f1 = *reinterpret_cast<const bf16x8*>((AB) + base_f + 512); \
    bf16x8 _f2 = *reinterpret_cast<const bf16x8*>((AB) + base_f + 1024); \
    bf16x8 _f3 = *reinterpret_cast<const bf16x8*>((AB) + base_f + 1536); \
    acc[0][0] = __builtin_amdgcn_mfma_f32_16x16x32_bf16(_f0, BS[0], acc[0][0], 0, 0, 0); \
    acc[0][1] = __builtin_amdgcn_mfma_f32_16x16x32_bf16(_f0, BS[1], acc[0][1], 0, 0, 0); \
    acc[0][2] = __builtin_amdgcn_mfma_f32_16x16x32_bf16(_f0, BS[2], acc[0][2], 0, 0, 0); \
    acc[0][3] = __builtin_amdgcn_mfma_f32_16x16x32_bf16(_f0, BS[3], acc[0][3], 0, 0, 0); \
    acc[1][0] = __builtin_amdgcn_mfma_f32_16x16x32_bf16(_f1, BS[0], acc[1][0], 0, 0, 0); \
    acc[1][1] = __builtin_amdgcn_mfma_f32_16x16x32_bf16(_f1, BS[1], acc[1][1], 0, 0, 0); \
    acc[1][2] = __builtin_amdgcn_mfma_f32_16x16x32_bf16(_f1, BS[2], acc[1][2], 0, 0, 0); \
    acc[1][3] = __builtin_amdgcn_mfma_f32_16x16x32_bf16(_f1, BS[3], acc[1][3], 0, 0, 0); \
    acc[2][0] = __builtin_amdgcn_mfma_f32_16x16x32_bf16(_f2, BS[0], acc[2][0], 0, 0, 0); \
    acc[2][1] = __builtin_amdgcn_mfma_f32_16x16x32_bf16(_f2, BS[1], acc[2][1], 0, 0, 0); \
    acc[2][2] = __builtin_amdgcn_mfma_f32_16x16x32_bf16(_f2, BS[2], acc[2][2], 0, 0, 0); \
    acc[2][3] = __builtin_amdgcn_mfma_f32_16x16x32_bf16(_f2, BS[3], acc[2][3], 0, 0, 0); \
    acc[3][0] = __builtin_amdgcn_mfma_f32_16x16x32_bf16(_f3, BS[0], acc[3][0], 0, 0, 0); \
    acc[3][1] = __builtin_amdgcn_mfma_f32_16x16x32_bf16(_f3, BS[1], acc[3][1], 0, 0, 0); \
    acc[3][2] = __builtin_amdgcn_mfma_f32_16x16x32_bf16(_f3, BS[2], acc[3][2], 0, 0, 0); \
    acc[3][3] = __builtin_amdgcn_mfma_f32_16x16x32_bf16(_f3, BS[3], acc[3][3], 0, 0, 0); \
  }
// iter J (pair P=J&1): barrier; gload raws for iter J+1; B(2J+1)->So;
// group0: frags As[2P] x Se(kb=2J); reload Se<-B(2J+2);
// group1: frags As[2P+1] x So; cvt raws -> pair 1-P; lgkmcnt(0)
#define K_ITER(J, PP, DO_G, DO_SE) {                                  \
    MEMBAR();                                                         \
    __builtin_amdgcn_s_barrier();                                     \
    MEMBAR();                                                         \
    if (DO_G) {                                                       \
      rawA = gp[((J) + 1) * 16 + c];                                  \
      rawB = gp[((J) + 1) * 16 + 8 + c];                              \
    }                                                                 \
    LOADB(So, 2 * (J) + 1);                                           \
    MEMBAR();                                                         \
    MFMA16(&As[2 * (PP)][0], Se)                                      \
    if (DO_SE) LOADB(Se, 2 * (J) + 2);                                \
    MFMA16(&As[2 * (PP) + 1][0], So)                                  \
    if (DO_G) {                                                       \
      CVT4W(2 * (1 - (PP)), rawA);                                    \
      CVT4W(2 * (1 - (PP)) + 1, rawB);                                \
    }                                                                 \
    asm volatile("s_waitcnt lgkmcnt(0)" ::: "memory");                \
  }

  // prologue: iter-0 pair staged to bufs 0/1; Se <- kb 0
  rawA = gp[c];
  rawB = gp[8 + c];
  CVT4W(0, rawA);
  CVT4W(1, rawB);
  LOADB(Se, 0);
  asm volatile("s_waitcnt lgkmcnt(0)" ::: "memory");

#pragma unroll 1
  for (int p = 0; p < 7; ++p) {
    const int j = p * 2;
    K_ITER(j,     0, 1, 1)
    K_ITER(j + 1, 1, 1, 1)
  }
  K_ITER(14, 0, 1, 1)
  K_ITER(15, 1, 0, 0)

#undef K_ITER
#undef MFMA16
#undef LOADB
#undef CVT4W

  // epilogue: x = acc + P[b][h]; part += v[h]*tanh(x); reduce over hl lanes
  float part[4][4];
#pragma unroll
  for (int mi = 0; mi < 4; ++mi)
#pragma unroll
    for (int rr = 0; rr < 4; ++rr) part[mi][rr] = 0.f;

#pragma unroll
  for (int ni = 0; ni < 4; ++ni) {
    const int h = w * 64 + ni * 16 + hl;
    const float ph = P[b * 512 + h];
    const float vh = v[h];
#pragma unroll
    for (int mi = 0; mi < 4; ++mi)
#pragma unroll
      for (int rr = 0; rr < 4; ++rr) {
        float x = acc[mi][ni][rr] + ph;
        float e = __expf(2.f * x);
        part[mi][rr] += vh * (1.f - 2.f * __frcp_rn(e + 1.f));
      }
  }
#pragma unroll
  for (int off = 1; off < 16; off <<= 1)
#pragma unroll
    for (int mi = 0; mi < 4; ++mi)
#pragma unroll
      for (int rr = 0; rr < 4; ++rr)
        part[mi][rr] += __shfl_xor(part[mi][rr], off, 16);

  if (hl == 0) {
#pragma unroll
    for (int mi = 0; mi < 4; ++mi)
#pragma unroll
      for (int rr = 0; rr < 4; ++rr)
        attred[mi * 16 + kg * 4 + rr][w] = part[mi][rr];
  }
  __syncthreads();
  if (tid < 64) {
    const float* a = attred[tid];
    logits[rowbase + tid] = ((a[0] + a[1]) + (a[2] + a[3])) +
                            ((a[4] + a[5]) + (a[6] + a[7]));
  }
}

// ---- K2: softmax over S=4096 per batch row
__global__ __launch_bounds__(256) void k_softmax(
    const float* __restrict__ logits, float* __restrict__ out) {
  const int b = blockIdx.x;
  const int t = threadIdx.x;
  const int wid = t >> 6, lane = t & 63;
  const float* L = logits + b * 4096;
  __shared__ float rmax[4], rsum[4];
  float lv[16];
  float m = -1e30f;
#pragma unroll
  for (int i = 0; i < 16; ++i) {
    lv[i] = L[t + i * 256];
    m = fmaxf(m, lv[i]);
  }
#pragma unroll
  for (int off = 32; off >= 1; off >>= 1) m = fmaxf(m, __shfl_xor(m, off));
  if (lane == 0) rmax[wid] = m;
  __syncthreads();
  m = fmaxf(fmaxf(rmax[0], rmax[1]), fmaxf(rmax[2], rmax[3]));
  float s = 0.f;
#pragma unroll
  for (int i = 0; i < 16; ++i) {
    lv[i] = __expf(lv[i] - m);
    s += lv[i];
  }
#pragma unroll
  for (int off = 32; off >= 1; off >>= 1) s += __shfl_xor(s, off);
  if (lane == 0) rsum[wid] = s;
  __syncthreads();
  s = rsum[0] + rsum[1] + rsum[2] + rsum[3];
  float inv = 1.0f / s;
#pragma unroll
  for (int i = 0; i < 16; ++i) out[b * 4096 + t + i * 256] = lv[i] * inv;
}

extern "C" void kernel_launch(void* const* d_in, const int* in_sizes, int n_in,
                              void* d_out, int out_size, void* d_ws, size_t ws_size,
                              hipStream_t stream) {
  const float* hidden = (const float*)d_in[0];   // [16,512]
  const float* enc    = (const float*)d_in[1];   // [16,4096,1024]
  const float* W      = (const float*)d_in[2];   // [512,1536]
  const float* bias   = (const float*)d_in[3];   // [512]
  const float* v      = (const float*)d_in[4];   // [512]
  float* out = (float*)d_out;                    // [16,4096]

  char* ws = (char*)d_ws;
  float* P = (float*)ws;                                       // 32 KB
  unsigned short* W2t = (unsigned short*)(ws + 32768);         // 1 MB
  float* logits = (float*)(ws + 32768 + 1048576);              // 256 KB

  k_prep_p<<<16, 256, 0, stream>>>(hidden, W, bias, P);
  k_prep_w<<<256, 256, 0, stream>>>(W, W2t);
  k_main<<<1024, 512, 0, stream>>>(enc, (const short*)W2t, P, v, logits);
  k_softmax<<<16, 256, 0, stream>>>(logits, out);
}

// Round 12
// 146.926 us; speedup vs baseline: 1.0889x; 1.0889x over previous
//
#include <hip/hip_runtime.h>

typedef __attribute__((ext_vector_type(4))) float f32x4;
typedef __attribute__((ext_vector_type(8))) short bf16x8;

#define MEMBAR() asm volatile("" ::: "memory")

__device__ __forceinline__ unsigned short f2bf(float f) {
  unsigned int u = __builtin_bit_cast(unsigned int, f);
  u += 0x7FFFu + ((u >> 16) & 1u);   // RTNE
  return (unsigned short)(u >> 16);
}

// ---- K0a: P[b][h] = b_attn[h] + dot(W_attn[h, 0:512], hidden[b, :])
__global__ __launch_bounds__(256) void k_prep_p(
    const float* __restrict__ hidden, const float* __restrict__ W,
    const float* __restrict__ bias, float* __restrict__ P) {
  __shared__ float hsh[512];
  const int b = blockIdx.x;
  for (int i = threadIdx.x; i < 512; i += 256) hsh[i] = hidden[b * 512 + i];
  __syncthreads();
  for (int h = threadIdx.x; h < 512; h += 256) {
    const float* wr = W + (long)h * 1536;
    float s = 0.f;
#pragma unroll 4
    for (int f = 0; f < 512; f += 4) {
      float4 wv = *reinterpret_cast<const float4*>(wr + f);
      s += wv.x * hsh[f] + wv.y * hsh[f + 1] + wv.z * hsh[f + 2] + wv.w * hsh[f + 3];
    }
    P[b * 512 + h] = bias[h] + s;
  }
}

// ---- K0b: W2t[kb][h][kk] = bf16(W_attn[h][512 + kb*32 + kk]),  kb<32, h<512, kk<32
__global__ __launch_bounds__(256) void k_prep_w(
    const float* __restrict__ W, unsigned short* __restrict__ W2t) {
  const int id = blockIdx.x * 256 + threadIdx.x;  // 65536 threads, 8 elems each
  const int kk8 = (id & 3) * 8;
  const int h = (id >> 2) & 511;
  const int kb = id >> 11;
  const float* src = W + (long)h * 1536 + 512 + kb * 32 + kk8;
  float4 a = *reinterpret_cast<const float4*>(src);
  float4 c = *reinterpret_cast<const float4*>(src + 4);
  union { unsigned short u[8]; bf16x8 v; } o;
  o.u[0] = f2bf(a.x); o.u[1] = f2bf(a.y); o.u[2] = f2bf(a.z); o.u[3] = f2bf(a.w);
  o.u[4] = f2bf(c.x); o.u[5] = f2bf(c.y); o.u[6] = f2bf(c.z); o.u[7] = f2bf(c.w);
  *reinterpret_cast<bf16x8*>(W2t + (long)kb * 16384 + h * 32 + kk8) = o.v;
}

// ---- K1: fused GEMM + tanh + v-reduce -> logits partials
// 2048 blocks = 1024 mtiles x 2 ntiles; 256 thr = 4 waves, wave 64x64.
// Block: 64 rows x 256 cols (colbase = ntile*256). Round-9 champion pipeline:
// reg-staged bf16 LDS (cvt-on-write), 4-buffer ring, one raw s_barrier/iter,
// lgkmcnt(0) only (never a vmcnt drain). 4-wave blocks give occupancy
// granularity: ~75 VGPR + 64 AGPR -> 3 blocks/CU = 12 waves/CU.
__global__ __launch_bounds__(256, 3) void k_main(
    const float* __restrict__ enc, const short* __restrict__ W2t,
    const float* __restrict__ P, const float* __restrict__ v,
    float* __restrict__ logits_part) {
  __shared__ short As[4][2048];        // 4 sub-bufs x [64 rows][32 k] bf16 = 16 KB
  __shared__ float attred[64][4];

  const int tid = threadIdx.x;
  const int lane = tid & 63;
  const int w = tid >> 6;               // 0..3: col panel w*64 within the 256
  const int hl = lane & 15, kg = lane >> 4;

  // XCD swizzle: the 2 ntiles of an mtile adjacent within one XCD stream
  const int bid = blockIdx.x;
  const int xcd = bid & 7, idx = bid >> 3;        // idx 0..255
  const int mtile = xcd * 128 + (idx >> 1);       // 0..1023
  const int ntile = idx & 1;
  const long rowbase = (long)mtile * 64;
  const int colbase = ntile * 256;
  const int b = (int)(rowbase >> 12);             // 64 | 4096

  // staging: thread -> row r = tid>>2, 8 floats at chunk c = tid&3 (c*8)
  const int r = tid >> 2, c = tid & 3;
  const float* ga = enc + (rowbase + r) * 1024 + c * 8;
  // swizzled write (shorts): 16B slot c ^ ((r>>1)&3)  [same algebra as r9]
  const int wr_off = r * 32 + ((c ^ ((r >> 1) & 3)) << 3);
  // frag read (shorts): row = mi*16+hl, slot = kg ^ ((hl>>1)&3)  [mi-invariant]
  const int base_f = hl * 32 + ((kg ^ ((hl >> 1) & 3)) << 3);
  // B: h = colbase + w*64 + ni*16 + hl; elem = kb*16384 + h*32 + kg*8
  const short* bp = W2t + (colbase + w * 64 + hl) * 32 + kg * 8;

  f32x4 acc[4][4];
#pragma unroll
  for (int mi = 0; mi < 4; ++mi)
#pragma unroll
    for (int ni = 0; ni < 4; ++ni) acc[mi][ni] = (f32x4){0.f, 0.f, 0.f, 0.f};

  bf16x8 Ba[4], Bb[4];
  f32x4 rawE0, rawE1, rawO0, rawO1;

#define CVT8W(BUF, R0, R1) {                                          \
    union { __bf16 h[8]; bf16x8 s; } _u;                              \
    _u.h[0] = (__bf16)(R0)[0]; _u.h[1] = (__bf16)(R0)[1];             \
    _u.h[2] = (__bf16)(R0)[2]; _u.h[3] = (__bf16)(R0)[3];             \
    _u.h[4] = (__bf16)(R1)[0]; _u.h[5] = (__bf16)(R1)[1];             \
    _u.h[6] = (__bf16)(R1)[2]; _u.h[7] = (__bf16)(R1)[3];             \
    *reinterpret_cast<bf16x8*>(&As[(BUF)][wr_off]) = _u.s;            \
  }
#define LOADB(DST, KB) {                                              \
    const short* _k = bp + (KB) * 16384;                              \
    DST[0] = *reinterpret_cast<const bf16x8*>(_k);                    \
    DST[1] = *reinterpret_cast<const bf16x8*>(_k + 512);              \
    DST[2] = *reinterpret_cast<const bf16x8*>(_k + 1024);             \
    DST[3] = *reinterpret_cast<const bf16x8*>(_k + 1536);             \
  }
#define MFMA16(AB, BS) {                                              \
    bf16x8 _f0 = *reinterpret_cast<const bf16x8*>((AB) + base_f);     \
    bf16x8 _f1 = *reinterpret_cast<const bf16x8*>((AB) + base_f + 512); \
    bf16x8 _f2 = *reinterpret_cast<const bf16x8*>((AB) + base_f + 1024); \
    bf16x8 _f3 = *reinterpret_cast<const bf16x8*>((AB) + base_f + 1536); \
    acc[0][0] = __builtin_amdgcn_mfma_f32_16x16x32_bf16(_f0, BS[0], acc[0][0], 0, 0, 0); \
    acc[0][1] = __builtin_amdgcn_mfma_f32_16x16x32_bf16(_f0, BS[1], acc[0][1], 0, 0, 0); \
    acc[0][2] = __builtin_amdgcn_mfma_f32_16x16x32_bf16(_f0, BS[2], acc[0][2], 0, 0, 0); \
    acc[0][3] = __builtin_amdgcn_mfma_f32_16x16x32_bf16(_f0, BS[3], acc[0][3], 0, 0, 0); \
    acc[1][0] = __builtin_amdgcn_mfma_f32_16x16x32_bf16(_f1, BS[0], acc[1][0], 0, 0, 0); \
    acc[1][1] = __builtin_amdgcn_mfma_f32_16x16x32_bf16(_f1, BS[1], acc[1][1], 0, 0, 0); \
    acc[1][2] = __builtin_amdgcn_mfma_f32_16x16x32_bf16(_f1, BS[2], acc[1][2], 0, 0, 0); \
    acc[1][3] = __builtin_amdgcn_mfma_f32_16x16x32_bf16(_f1, BS[3], acc[1][3], 0, 0, 0); \
    acc[2][0] = __builtin_amdgcn_mfma_f32_16x16x32_bf16(_f2, BS[0], acc[2][0], 0, 0, 0); \
    acc[2][1] = __builtin_amdgcn_mfma_f32_16x16x32_bf16(_f2, BS[1], acc[2][1], 0, 0, 0); \
    acc[2][2] = __builtin_amdgcn_mfma_f32_16x16x32_bf16(_f2, BS[2], acc[2][2], 0, 0, 0); \
    acc[2][3] = __builtin_amdgcn_mfma_f32_16x16x32_bf16(_f2, BS[3], acc[2][3], 0, 0, 0); \
    acc[3][0] = __builtin_amdgcn_mfma_f32_16x16x32_bf16(_f3, BS[0], acc[3][0], 0, 0, 0); \
    acc[3][1] = __builtin_amdgcn_mfma_f32_16x16x32_bf16(_f3, BS[1], acc[3][1], 0, 0, 0); \
    acc[3][2] = __builtin_amdgcn_mfma_f32_16x16x32_bf16(_f3, BS[2], acc[3][2], 0, 0, 0); \
    acc[3][3] = __builtin_amdgcn_mfma_f32_16x16x32_bf16(_f3, BS[3], acc[3][3], 0, 0, 0); \
  }
// iter J: barrier; gload tile J+2 -> RL*; B(J+1) -> BOUT; MFMA on buf[J&3] x BIN;
//         cvt RC* (tile J+1) -> buf[(J+1)&3]; lgkmcnt(0)
#define K_ITER(J, RC0, RC1, RL0, RL1, BIN, BOUT, DO_G, DO_B, DO_CVT) {\
    MEMBAR();                                                         \
    __builtin_amdgcn_s_barrier();                                     \
    MEMBAR();                                                         \
    if (DO_G) {                                                       \
      RL0 = *reinterpret_cast<const f32x4*>(ga + ((J) + 2) * 32);     \
      RL1 = *reinterpret_cast<const f32x4*>(ga + ((J) + 2) * 32 + 4); \
    }                                                                 \
    if (DO_B) LOADB(BOUT, (J) + 1);                                   \
    MEMBAR();                                                         \
    MFMA16(&As[(J) & 3][0], BIN)                                      \
    if (DO_CVT) CVT8W(((J) + 1) & 3, RC0, RC1);                       \
    asm volatile("s_waitcnt lgkmcnt(0)" ::: "memory");                \
  }

  // prologue: tile0 -> buf0; tile1 -> rawO; B(0) -> Ba
  rawE0 = *reinterpret_cast<const f32x4*>(ga);
  rawE1 = *reinterpret_cast<const f32x4*>(ga + 4);
  CVT8W(0, rawE0, rawE1);
  rawO0 = *reinterpret_cast<const f32x4*>(ga + 32);
  rawO1 = *reinterpret_cast<const f32x4*>(ga + 36);
  LOADB(Ba, 0);
  __syncthreads();

#pragma unroll 1
  for (int p = 0; p < 15; ++p) {
    const int j = p * 2;
    K_ITER(j,     rawO0, rawO1, rawE0, rawE1, Ba, Bb, 1, 1, 1)
    K_ITER(j + 1, rawE0, rawE1, rawO0, rawO1, Bb, Ba, 1, 1, 1)
  }
  K_ITER(30, rawO0, rawO1, rawE0, rawE1, Ba, Bb, 0, 1, 1)
  K_ITER(31, rawE0, rawE1, rawO0, rawO1, Bb, Ba, 0, 0, 0)

#undef K_ITER
#undef MFMA16
#undef LOADB
#undef CVT8W

  // epilogue: x = acc + P[b][h]; part += v[h]*tanh(x); reduce over hl lanes
  float part[4][4];
#pragma unroll
  for (int mi = 0; mi < 4; ++mi)
#pragma unroll
    for (int rr = 0; rr < 4; ++rr) part[mi][rr] = 0.f;

#pragma unroll
  for (int ni = 0; ni < 4; ++ni) {
    const int h = colbase + w * 64 + ni * 16 + hl;
    const float ph = P[b * 512 + h];
    const float vh = v[h];
#pragma unroll
    for (int mi = 0; mi < 4; ++mi)
#pragma unroll
      for (int rr = 0; rr < 4; ++rr) {
        float x = acc[mi][ni][rr] + ph;
        float e = __expf(2.f * x);
        part[mi][rr] += vh * (1.f - 2.f * __frcp_rn(e + 1.f));
      }
  }
#pragma unroll
  for (int off = 1; off < 16; off <<= 1)
#pragma unroll
    for (int mi = 0; mi < 4; ++mi)
#pragma unroll
      for (int rr = 0; rr < 4; ++rr)
        part[mi][rr] += __shfl_xor(part[mi][rr], off, 16);

  __syncthreads();   // K-loop done in all waves before reusing LDS region
  if (hl == 0) {
#pragma unroll
    for (int mi = 0; mi < 4; ++mi)
#pragma unroll
      for (int rr = 0; rr < 4; ++rr)
        attred[mi * 16 + kg * 4 + rr][w] = part[mi][rr];
  }
  __syncthreads();
  if (tid < 64) {
    const float* a = attred[tid];
    logits_part[ntile * 65536 + rowbase + tid] =
        (a[0] + a[1]) + (a[2] + a[3]);
  }
}

// ---- K2: softmax over S=4096 per batch row; input = sum of the 2 h-partials
__global__ __launch_bounds__(256) void k_softmax(
    const float* __restrict__ logits_part, float* __restrict__ out) {
  const int b = blockIdx.x;
  const int t = threadIdx.x;
  const int wid = t >> 6, lane = t & 63;
  const float* L0 = logits_part + b * 4096;
  const float* L1 = logits_part + 65536 + b * 4096;
  __shared__ float rmax[4], rsum[4];
  float lv[16];
  float m = -1e30f;
#pragma unroll
  for (int i = 0; i < 16; ++i) {
    const int j = t + i * 256;
    lv[i] = L0[j] + L1[j];
    m = fmaxf(m, lv[i]);
  }
#pragma unroll
  for (int off = 32; off >= 1; off >>= 1) m = fmaxf(m, __shfl_xor(m, off));
  if (lane == 0) rmax[wid] = m;
  __syncthreads();
  m = fmaxf(fmaxf(rmax[0], rmax[1]), fmaxf(rmax[2], rmax[3]));
  float s = 0.f;
#pragma unroll
  for (int i = 0; i < 16; ++i) {
    lv[i] = __expf(lv[i] - m);
    s += lv[i];
  }
#pragma unroll
  for (int off = 32; off >= 1; off >>= 1) s += __shfl_xor(s, off);
  if (lane == 0) rsum[wid] = s;
  __syncthreads();
  s = rsum[0] + rsum[1] + rsum[2] + rsum[3];
  float inv = 1.0f / s;
#pragma unroll
  for (int i = 0; i < 16; ++i) out[b * 4096 + t + i * 256] = lv[i] * inv;
}

extern "C" void kernel_launch(void* const* d_in, const int* in_sizes, int n_in,
                              void* d_out, int out_size, void* d_ws, size_t ws_size,
                              hipStream_t stream) {
  const float* hidden = (const float*)d_in[0];   // [16,512]
  const float* enc    = (const float*)d_in[1];   // [16,4096,1024]
  const float* W      = (const float*)d_in[2];   // [512,1536]
  const float* bias   = (const float*)d_in[3];   // [512]
  const float* v      = (const float*)d_in[4];   // [512]
  float* out = (float*)d_out;                    // [16,4096]

  char* ws = (char*)d_ws;
  float* P = (float*)ws;                                       // 32 KB
  unsigned short* W2t = (unsigned short*)(ws + 32768);         // 1 MB
  float* logits_part = (float*)(ws + 32768 + 1048576);         // 2 x 256 KB

  k_prep_p<<<16, 256, 0, stream>>>(hidden, W, bias, P);
  k_prep_w<<<256, 256, 0, stream>>>(W, W2t);
  k_main<<<2048, 256, 0, stream>>>(enc, (const short*)W2t, P, v, logits_part);
  k_softmax<<<16, 256, 0, stream>>>(logits_part, out);
}